// Round 1
// baseline (352.463 us; speedup 1.0000x reference)
//
#include <hip/hip_runtime.h>

#define WW   320
#define HH   160
#define CIN  80
#define COUT 32
#define DD   48
#define NB   8
#define VP2  68   // vol row pad (f32 words), pass width 64

typedef __bf16 bf16x8 __attribute__((ext_vector_type(8)));
typedef float  float4v __attribute__((ext_vector_type(4)));

// One block per (b,h) row; 320 threads = 5 waves, each wave OWNS w-slice
// [64*wave, 64*wave+64). R2 restructure vs R1:
//  - P1 operand swap: x is the A operand (m=w, k=c) loaded global->regs
//    directly (no xs2 LDS staging, NO barriers in P1, 2-deep prefetch);
//    BN-folded weights are the B operand (n=o), built once in regs.
//    Bias folded into MFMA C-init (D col = o = ln15 is lane-constant).
//  - D[w][o] (+already-biased) -> fLs/fRs bf16 [w][32] XOR-swizzled via
//    32 scalar b16 LDS writes/lane (~2-way conflicts = free).
//  - P2 identical banded-volume scheme but 5 passes of 64 w (vol 48x68 f32)
//    so total LDS = 20480+20480+13056+128 = 54144 B -> 3 blocks/CU
//    (15 waves/CU vs 10). scs/shs/scratch alias the then-dead fLs region.
__global__ __launch_bounds__(320, 4)   // forces VGPR<=128 so 15 waves fit
void vol_kernel(const float* __restrict__ inL, const float* __restrict__ inR,
                const float* __restrict__ gamma, const float* __restrict__ beta,
                const float* __restrict__ bnmean, const float* __restrict__ bnvar,
                const float* __restrict__ convw, const float* __restrict__ convb,
                float* __restrict__ out)
{
    __shared__ __align__(16) __bf16 fLs[WW * COUT];   // 20480 B
    __shared__ __align__(16) __bf16 fRs[WW * COUT];   // 20480 B
    __shared__ __align__(16) float  vol[DD * VP2];    // 13056 B (P2 only)
    __shared__ float biasp[32];                       // 128 B

    // P0 scratch aliases fLs (dead until P1 epilogue; barrier #3 separates)
    float* scs     = (float*)fLs;      // [96]  (zero-pad 80..95)
    float* shs     = scs + 96;         // [80]
    float* scratch = shs + 80;         // [320]

    const int t = threadIdx.x;
    const int b = blockIdx.x / HH;
    const int h = blockIdx.x % HH;
    const size_t HW = (size_t)HH * WW;
    const int wave = t >> 6, lane = t & 63, ln15 = lane & 15, quad = lane >> 4;
    const int wb = wave * 64;          // this wave's private w-slice base

    // ---------------- P0a: BN folds ----------------
    if (t < CIN) {
        float sc = gamma[t] * rsqrtf(bnvar[t] + 1e-5f);
        scs[t] = sc;
        shs[t] = fmaf(-bnmean[t], sc, beta[t]);
    } else if (t < 96) {
        scs[t] = 0.f;
    }
    __syncthreads();   // #1

    // ---------------- P0b: weight B-frags (regs) + bias partials ----------
    // B[k=c][n=o] = W[o][c]*sc_c : lane(ln15=o, quad=k-oct), 8 elems
    bf16x8 bfr[2][3];   // [o-tile][k-chunk]
    #pragma unroll
    for (int ot = 0; ot < 2; ++ot) {
        #pragma unroll
        for (int kk = 0; kk < 3; ++kk) {
            const int c0 = kk * 32 + quad * 8;
            bf16x8 a;
            if (c0 < CIN) {           // c0 multiple of 8; no straddle at 80
                const float* wp = convw + (ot * 16 + ln15) * CIN + c0;
                float4v w0 = *(const float4v*)wp;
                float4v w1 = *(const float4v*)(wp + 4);
                float4v s0 = *(const float4v*)(scs + c0);
                float4v s1 = *(const float4v*)(scs + c0 + 4);
                #pragma unroll
                for (int j = 0; j < 4; ++j) {
                    a[j]     = (__bf16)(w0[j] * s0[j]);
                    a[j + 4] = (__bf16)(w1[j] * s1[j]);
                }
            } else {
                #pragma unroll
                for (int j = 0; j < 8; ++j) a[j] = (__bf16)0.f;
            }
            bfr[ot][kk] = a;
        }
    }
    {   // bias partials: thread (o=t&31, part=t>>5) does 8 FMAs
        const int o = t & 31, part = t >> 5;
        float p = 0.f;
        #pragma unroll
        for (int j = 0; j < 8; ++j) {
            int c = part * 8 + j;
            p = fmaf(shs[c], convw[o * CIN + c], p);
        }
        scratch[part * 32 + o] = p;
    }
    __syncthreads();   // #2
    if (t < 32) {
        float s = convb[t];
        #pragma unroll
        for (int pt = 0; pt < 10; ++pt) s += scratch[pt * 32 + t];
        biasp[t] = s;
    }
    __syncthreads();   // #3 — biasp visible; P0 aliases in fLs now dead

    // ---------------- P1: preconv, per image, BARRIER-FREE ----------------
    #pragma unroll 1
    for (int img = 0; img < 2; ++img) {
        const float* __restrict__ pbase =
            (img ? inR : inL) + ((size_t)b * CIN * HH + h) * WW;
        __bf16* f = img ? fRs : fLs;

        const float bi0 = biasp[ln15];
        const float bi1 = biasp[16 + ln15];
        float4v acc[4][2];
        #pragma unroll
        for (int nt = 0; nt < 4; ++nt) {
            acc[nt][0] = (float4v){bi0, bi0, bi0, bi0};
            acc[nt][1] = (float4v){bi1, bi1, bi1, bi1};
        }

        // A-frag source: lane(ln15,quad) needs x[w=wb+nt*16+ln15][c=kk*32+quad*8+j]
        // 8 strided dwords; 16-lane groups are 64B-coalesced.
        float y[3][8];   // 2-deep prefetch ring (all indices const after unroll)
        auto LOADF = [&](int ft, float (&yy)[8]) {
            const int nt = ft / 3, kk = ft - nt * 3;
            if (kk == 2 && quad >= 2) {           // c >= 80: zero-fill (no NaN/Inf)
                #pragma unroll
                for (int j = 0; j < 8; ++j) yy[j] = 0.f;
            } else {
                const float* pp = pbase + (size_t)(kk * 32 + quad * 8) * HW
                                        + (wb + nt * 16 + ln15);
                #pragma unroll
                for (int j = 0; j < 8; ++j) yy[j] = pp[(size_t)j * HW];
            }
        };

        LOADF(0, y[0]);
        LOADF(1, y[1]);
        #pragma unroll
        for (int ft = 0; ft < 12; ++ft) {
            if (ft < 10) LOADF(ft + 2, y[(ft + 2) % 3]);
            const int nt = ft / 3, kk = ft - nt * 3;
            bf16x8 a;
            {
                float (&yy)[8] = y[ft % 3];
                #pragma unroll
                for (int j = 0; j < 8; ++j) a[j] = (__bf16)fmaxf(yy[j], 0.f);
            }
            acc[nt][0] = __builtin_amdgcn_mfma_f32_16x16x32_bf16(a, bfr[0][kk], acc[nt][0], 0, 0, 0);
            acc[nt][1] = __builtin_amdgcn_mfma_f32_16x16x32_bf16(a, bfr[1][kk], acc[nt][1], 0, 0, 0);
        }

        // D layout: row(m)=quad*4+r -> w offset, col(n)=ln15 -> o.
        // Write bf16 [w][32], XOR-swizzled: elem (w,o) at
        //   w*32 + (((o>>3) ^ ((w>>1)&3))<<3) + (o&7)
        #pragma unroll
        for (int nt = 0; nt < 4; ++nt) {
            const int wr0 = wb + nt * 16 + quad * 4;
            #pragma unroll
            for (int r = 0; r < 4; ++r) {
                const int w  = wr0 + r;
                const int sw = (w >> 1) & 3;
                #pragma unroll
                for (int ot = 0; ot < 2; ++ot) {
                    const int o = ot * 16 + ln15;
                    f[w * 32 + ((((o >> 3) ^ sw)) << 3) + (o & 7)] =
                        (__bf16)acc[nt][ot][r];
                }
            }
        }
    }
    __syncthreads();   // #4 — fLs/fRs complete

    // ---------------- P2: banded volume via MFMA, 5 passes of 64 w --------
    #pragma unroll 1
    for (int pass = 0; pass < 5; ++pass) {
        for (int k = wave; k < 16; k += 5) {
            const int two = k >> 2;            // w-tile within pass: 0..3
            const int d   = k & 3;             // j-tile lag: 0..3
            const int tw  = pass * 4 + two;
            const int tj  = tw - d;
            if (tj >= 0) {
                const int wr = tw * 16 + ln15;  // A row (w)
                const int jr = tj * 16 + ln15;  // B row (j)
                bf16x8 av = *(const bf16x8*)(fLs + wr * 32 +
                                             ((quad ^ ((wr >> 1) & 3)) << 3));
                bf16x8 bv = *(const bf16x8*)(fRs + jr * 32 +
                                             ((quad ^ ((jr >> 1) & 3)) << 3));
                float4v cz = {0.f, 0.f, 0.f, 0.f};
                float4v dv = __builtin_amdgcn_mfma_f32_16x16x32_bf16(av, bv, cz, 0, 0, 0);
                #pragma unroll
                for (int r = 0; r < 4; ++r) {
                    int row = quad * 4 + r;
                    int i = 16 * d + row - ln15;   // disparity
                    if (i >= 0 && i < DD)
                        vol[i * VP2 + two * 16 + row] = dv[r] * (1.f / 32.f);
                }
            }
        }
        __syncthreads();

        // coalesced float4 store of 48 x 64 chunk; w<i band forced to 0
        for (int s = t; s < DD * 16; s += 320) {
            int i = s >> 4, q = s & 15;
            int w0 = pass * 64 + q * 4;
            float4v v = *(const float4v*)(vol + i * VP2 + q * 4);
            #pragma unroll
            for (int e = 0; e < 4; ++e)
                if (w0 + e < i) v[e] = 0.f;
            *(float4v*)(out + ((size_t)(b * DD + i) * HH + h) * WW + w0) = v;
        }
        __syncthreads();
    }
}

extern "C" void kernel_launch(void* const* d_in, const int* in_sizes, int n_in,
                              void* d_out, int out_size, void* d_ws, size_t ws_size,
                              hipStream_t stream) {
    const float* inL    = (const float*)d_in[0];
    const float* inR    = (const float*)d_in[1];
    const float* gamma  = (const float*)d_in[2];
    const float* beta   = (const float*)d_in[3];
    const float* bnmean = (const float*)d_in[4];
    const float* bnvar  = (const float*)d_in[5];
    const float* convw  = (const float*)d_in[6];
    const float* convb  = (const float*)d_in[7];
    float* out = (float*)d_out;

    dim3 grid(NB * HH);   // 1280 row-blocks
    dim3 block(320);
    vol_kernel<<<grid, block, 0, stream>>>(inL, inR, gamma, beta, bnmean, bnvar,
                                           convw, convb, out);
}

// Round 2
// 330.876 us; speedup vs baseline: 1.0652x; 1.0652x over previous
//
#include <hip/hip_runtime.h>

#define WW   320
#define HH   160
#define CIN  80
#define COUT 32
#define DD   48
#define NB   8
#define VP   84   // vol row pad (f32 words)

typedef __bf16 bf16x8 __attribute__((ext_vector_type(8)));
typedef __bf16 bf16x4 __attribute__((ext_vector_type(4)));
typedef float  float4v __attribute__((ext_vector_type(4)));

// One block per (b,h) row; t == w (320 threads, 5 waves).
// R3 = R1 (best known: 138 us/dispatch) + NON-TEMPORAL output stores.
// Rationale: effective BW is invariant ~1.5 TB/s across R1/R2; time tracks
// HBM bytes. Inputs (262 MB) nearly fit L3 (256 MB) and are re-read every
// bench iteration; the 78.6 MB/iter of output (never re-read) evicts them.
// NT stores keep out of L3 -> inputs stay resident -> FETCH_SIZE drops.
__global__ __launch_bounds__(320, 2)
void vol_kernel(const float* __restrict__ inL, const float* __restrict__ inR,
                const float* __restrict__ gamma, const float* __restrict__ beta,
                const float* __restrict__ bnmean, const float* __restrict__ bnvar,
                const float* __restrict__ convw, const float* __restrict__ convb,
                float* __restrict__ out)
{
    __shared__ __align__(16) __bf16 fLs[WW * COUT];       // 20480 B
    __shared__ __align__(16) __bf16 fRs[WW * COUT];       // 20480 B
    __shared__ __align__(16) char   uni[WW * COUT * 2];   // 20480 B: xs2 | vol
    __shared__ __align__(16) float  scs[96];              // sc (zero-pad 80..95)
    __shared__ float  shs[80];
    __shared__ float  biasp[32];
    __shared__ float  scratch[320];

    __bf16* xs2 = (__bf16*)uni;        // [320][32] bf16, swizzled
    float*  vol = (float*)uni;         // [48][84] f32 (phase 2 only)

    const int t = threadIdx.x;         // == w
    const int b = blockIdx.x / HH;
    const int h = blockIdx.x % HH;
    const size_t HW = (size_t)HH * WW;
    const int wave = t >> 6, lane = t & 63, ln15 = lane & 15, quad = lane >> 4;
    const int w = t;
    const int sw = (w >> 1) & 3;       // xor-swizzle key for this thread's row

    // ---------------- P0a: BN folds ----------------
    if (t < CIN) {
        float sc = gamma[t] * rsqrtf(bnvar[t] + 1e-5f);
        scs[t] = sc;
        shs[t] = fmaf(-bnmean[t], sc, beta[t]);
    } else if (t < 96) {
        scs[t] = 0.f;
    }
    __syncthreads();

    // ---------------- P0b: weight A-frags (regs) + bias partials ----------
    bf16x8 afr[2][3];   // [m-tile][k-chunk]; A[m=o][k=c] = W[o][c]*sc_c
    #pragma unroll
    for (int mt = 0; mt < 2; ++mt) {
        #pragma unroll
        for (int kk = 0; kk < 3; ++kk) {
            const int c0 = kk * 32 + quad * 8;
            bf16x8 a;
            if (c0 < CIN) {           // c0 multiple of 8; 80-c0 too -> no straddle
                const float* wp = convw + (mt * 16 + ln15) * CIN + c0;
                float4v w0 = *(const float4v*)wp;
                float4v w1 = *(const float4v*)(wp + 4);
                float4v s0 = *(const float4v*)(scs + c0);
                float4v s1 = *(const float4v*)(scs + c0 + 4);
                #pragma unroll
                for (int j = 0; j < 4; ++j) {
                    a[j]     = (__bf16)(w0[j] * s0[j]);
                    a[j + 4] = (__bf16)(w1[j] * s1[j]);
                }
            } else {
                #pragma unroll
                for (int j = 0; j < 8; ++j) a[j] = (__bf16)0.f;
            }
            afr[mt][kk] = a;
        }
    }
    {   // bias partials: thread (o=t&31, part=t>>5) does 8 FMAs
        const int o = t & 31, part = t >> 5;
        float p = 0.f;
        #pragma unroll
        for (int j = 0; j < 8; ++j) {
            int c = part * 8 + j;
            p = fmaf(shs[c], convw[o * CIN + c], p);
        }
        scratch[part * 32 + o] = p;
    }
    __syncthreads();
    if (t < 32) {
        float s = convb[t];
        #pragma unroll
        for (int pt = 0; pt < 10; ++pt) s += scratch[pt * 32 + t];
        biasp[t] = s;   // visible to all after next barrier (inside P1)
    }

    // ---------------- P1: preconv via MFMA, per image ----------------
    #pragma unroll 1
    for (int img = 0; img < 2; ++img) {
        const float* __restrict__ px =
            (img ? inR : inL) + ((size_t)b * CIN * HH + h) * WW + w;
        __bf16* f = img ? fRs : fLs;

        float4v acc[2][4];
        #pragma unroll
        for (int mt = 0; mt < 2; ++mt)
            #pragma unroll
            for (int nn = 0; nn < 4; ++nn) acc[mt][nn] = (float4v){0.f, 0.f, 0.f, 0.f};

        float y[32];
        // stage chunk 0
        #pragma unroll
        for (int u = 0; u < 32; ++u) y[u] = px[(size_t)u * HW];
        #pragma unroll
        for (int g = 0; g < 4; ++g) {
            bf16x8 pk;
            #pragma unroll
            for (int j = 0; j < 8; ++j) pk[j] = (__bf16)fmaxf(y[g * 8 + j], 0.f);
            *(bf16x8*)(xs2 + w * 32 + ((g ^ sw) << 3)) = pk;
        }
        __syncthreads();

        #pragma unroll
        for (int kk = 0; kk < 3; ++kk) {
            if (kk < 2) {               // prefetch chunk kk+1 (regs, overlaps MFMA)
                #pragma unroll
                for (int u = 0; u < 32; ++u) {
                    int c = (kk + 1) * 32 + u;
                    y[u] = (c < CIN) ? px[(size_t)c * HW] : 0.f;
                }
            }
            #pragma unroll
            for (int nn = 0; nn < 4; ++nn) {
                const int wr = (nn * 5 + wave) * 16 + ln15;   // n = w
                bf16x8 bv = *(const bf16x8*)(xs2 + wr * 32 +
                                             ((quad ^ ((wr >> 1) & 3)) << 3));
                acc[0][nn] = __builtin_amdgcn_mfma_f32_16x16x32_bf16(afr[0][kk], bv, acc[0][nn], 0, 0, 0);
                acc[1][nn] = __builtin_amdgcn_mfma_f32_16x16x32_bf16(afr[1][kk], bv, acc[1][nn], 0, 0, 0);
            }
            __syncthreads();            // all reads of xs2 done
            if (kk < 2) {
                #pragma unroll
                for (int g = 0; g < 4; ++g) {
                    bf16x8 pk;
                    #pragma unroll
                    for (int j = 0; j < 8; ++j) pk[j] = (__bf16)fmaxf(y[g * 8 + j], 0.f);
                    *(bf16x8*)(xs2 + w * 32 + ((g ^ sw) << 3)) = pk;
                }
                __syncthreads();        // staged for next iter
            }
        }

        // D (+bias) -> f bf16 [w][o], swizzled. D: row(m=o)=quad*4+r, col(n=w)=ln15
        #pragma unroll
        for (int nn = 0; nn < 4; ++nn) {
            const int wg  = (nn * 5 + wave) * 16 + ln15;
            const int swg = (wg >> 1) & 3;
            #pragma unroll
            for (int mt = 0; mt < 2; ++mt) {
                float4v bi = *(const float4v*)(biasp + mt * 16 + quad * 4);
                bf16x4 o4;
                #pragma unroll
                for (int r = 0; r < 4; ++r)
                    o4[r] = (__bf16)(acc[mt][nn][r] + bi[r]);
                const int g = 2 * mt + (quad >> 1);
                *(bf16x4*)(f + wg * 32 + ((g ^ swg) << 3) + (quad & 1) * 4) = o4;
            }
        }
    }
    __syncthreads();

    // ---------------- P2: banded volume via MFMA (as R1) ----------------
    for (int pass = 0; pass < 4; ++pass) {
        for (int k = wave; k < 20; k += 5) {
            const int two = k >> 2;            // w-tile within pass: 0..4
            const int d   = k & 3;             // j-tile lag: 0..3
            const int tw  = pass * 5 + two;
            const int tj  = tw - d;
            if (tj >= 0) {
                const int wr = tw * 16 + ln15;  // A row (w)
                const int jr = tj * 16 + ln15;  // B row (j)
                bf16x8 av = *(const bf16x8*)(fLs + wr * 32 +
                                             ((quad ^ ((wr >> 1) & 3)) << 3));
                bf16x8 bv = *(const bf16x8*)(fRs + jr * 32 +
                                             ((quad ^ ((jr >> 1) & 3)) << 3));
                float4v cz = {0.f, 0.f, 0.f, 0.f};
                float4v dv = __builtin_amdgcn_mfma_f32_16x16x32_bf16(av, bv, cz, 0, 0, 0);
                #pragma unroll
                for (int r = 0; r < 4; ++r) {
                    int row = quad * 4 + r;
                    int i = 16 * d + row - ln15;   // disparity
                    if (i >= 0 && i < DD)
                        vol[i * VP + two * 16 + row] = dv[r] * (1.f / 32.f);
                }
            }
        }
        __syncthreads();

        // coalesced float4 NON-TEMPORAL store of 48 x 80 chunk; w<i band -> 0
        for (int s = t; s < DD * 20; s += 320) {
            int i = s / 20, q = s - i * 20;
            int wg0 = pass * 80 + q * 4;
            float4v v = *(const float4v*)(vol + i * VP + q * 4);
            #pragma unroll
            for (int e = 0; e < 4; ++e)
                if (wg0 + e < i) v[e] = 0.f;
            __builtin_nontemporal_store(
                v, (float4v*)(out + ((size_t)(b * DD + i) * HH + h) * WW + wg0));
        }
        __syncthreads();
    }
}

extern "C" void kernel_launch(void* const* d_in, const int* in_sizes, int n_in,
                              void* d_out, int out_size, void* d_ws, size_t ws_size,
                              hipStream_t stream) {
    const float* inL    = (const float*)d_in[0];
    const float* inR    = (const float*)d_in[1];
    const float* gamma  = (const float*)d_in[2];
    const float* beta   = (const float*)d_in[3];
    const float* bnmean = (const float*)d_in[4];
    const float* bnvar  = (const float*)d_in[5];
    const float* convw  = (const float*)d_in[6];
    const float* convb  = (const float*)d_in[7];
    float* out = (float*)d_out;

    dim3 grid(NB * HH);   // 1280 row-blocks
    dim3 block(320);
    vol_kernel<<<grid, block, 0, stream>>>(inL, inR, gamma, beta, bnmean, bnvar,
                                           convw, convb, out);
}